// Round 11
// baseline (48.655 us; speedup 1.0000x reference)
//
#include <hip/hip_runtime.h>

// PROBE ROUND v2: exact R8 body executed THREE times (rep loop + asm liveness
// barriers). R10's 2-rep probe measured marginal body cost 13.5us/rep but at
// 34.9us total still hid under the 38-41us harness memsets in the top-5 table.
// 3 reps => ~48us: the kernel's rocprof row (VGPR/Occupancy/VALUBusy) surfaces.
// Output identical to R8 (each rep recomputes the same values; one write).
//
// Bit-exactness (validated absmax 0.0 R4-R10): Markstein div == RN div via exact
// y=RN(1/rd); contract(off) for p=ro+t*rd; pair-split strict-< combine; own-axis
// band check elided. NEW: best init = BIG (not inf) so the keep-true/no-valid-
// candidate edge case emits BIG exactly like the reference.

typedef float v2f __attribute__((ext_vector_type(2)));

constexpr int BMAX = 32;
constexpr int HALF = BMAX / 2;

__global__ __launch_bounds__(256) void ray_aabb_kernel(
    const float* __restrict__ rays_o,
    const float* __restrict__ rays_d,
    const float* __restrict__ bbox,
    float* __restrict__ out_idx,
    float* __restrict__ out_dist,
    int R)
{
    const float BIG = 10000000000.0f;
    const float EPS = 1e-4f;

    // Per box: q0=(lo0,hi0,lo1,hi1)  q1=(lo2,hi2,loE0,loE1)  q2=(loE2,hiE0,hiE1,hiE2)
    __shared__ float4 s_q[BMAX][3];

    int t = threadIdx.x;
    if (t < BMAX) {
        int b = t;
        float lo[3], hi[3], loE[3], hiE[3];
        #pragma unroll
        for (int a = 0; a < 3; ++a) {
            float c = bbox[b * 6 + a];
            float s = bbox[b * 6 + 3 + a];
            float h  = __fmul_rn(s, 0.5f);
            lo[a]  = __fsub_rn(c, h);
            hi[a]  = __fadd_rn(c, h);
            loE[a] = __fsub_rn(lo[a], EPS);
            hiE[a] = __fadd_rn(hi[a], EPS);
        }
        s_q[b][0] = make_float4(lo[0], hi[0], lo[1], hi[1]);
        s_q[b][1] = make_float4(lo[2], hi[2], loE[0], loE[1]);
        s_q[b][2] = make_float4(loE[2], hiE[0], hiE[1], hiE[2]);
    }
    __syncthreads();

    // 2 threads per ray: parity selects box half.
    int gid  = blockIdx.x * blockDim.x + threadIdx.x;
    int ray  = gid >> 1;
    int par  = gid & 1;          // 0: boxes [0,16)  1: boxes [16,32)
    if (ray >= R) return;
    int b0   = par * HALF;

    float ro[3], rd[3], y[3];
    #pragma unroll
    for (int a = 0; a < 3; ++a) {
        ro[a] = rays_o[ray * 3 + a];
        float d = rays_d[ray * 3 + a];
        rd[a] = (d == 0.0f) ? 1e-8f : d;
        y[a]  = __fdiv_rn(1.0f, rd[a]);   // exact RN reciprocal (Markstein precondition)
    }

    bool  keep  = false;
    float best  = BIG;
    int   bestb = b0;

    for (int rep = 0; rep < 3; ++rep) {
        // Liveness barrier on inputs: reps cannot CSE with each other.
        #pragma unroll
        for (int a = 0; a < 3; ++a) {
            asm volatile("" : "+v"(ro[a]), "+v"(rd[a]), "+v"(y[a]));
        }
        keep  = false;
        best  = BIG;   // all-invalid half => (BIG, b0); matches np argmin-of-all-BIG
        bestb = b0;

        #pragma unroll 4
        for (int bi = 0; bi < HALF; ++bi) {
            int b = b0 + bi;
            float4 q0 = s_q[b][0];
            float4 q1 = s_q[b][1];
            float4 q2 = s_q[b][2];
            v2f bnd[3];                    // {lo,hi} per axis
            bnd[0] = v2f{q0.x, q0.y};
            bnd[1] = v2f{q0.z, q0.w};
            bnd[2] = v2f{q1.x, q1.y};
            float loE[3] = {q1.z, q1.w, q2.x};
            float hiE[3] = {q2.y, q2.z, q2.w};

            float entry[3], exitv[3];
            #pragma unroll
            for (int a = 0; a < 3; ++a) {
                v2f ys  = v2f{y[a], y[a]};
                v2f rs  = v2f{rd[a], rd[a]};
                v2f d2  = bnd[a] - v2f{ro[a], ro[a]};               // pk sub
                v2f q0v = d2 * ys;                                   // pk mul
                v2f e   = __builtin_elementwise_fma(rs, -q0v, d2);   // pk fma (exact residual)
                v2f qv  = __builtin_elementwise_fma(e, ys, q0v);     // pk fma == RN(d2/rd)
                entry[a] = fminf(qv.x, qv.y);
                exitv[a] = fmaxf(qv.x, qv.y);
            }
            float tmm = fmaxf(entry[0], fmaxf(entry[1], entry[2]));
            float tmx = fminf(exitv[0], fminf(exitv[1], exitv[2]));
            keep = keep || ((tmm < tmx) && (tmx > 0.0f));

            bool inb[3][3];
            #pragma unroll
            for (int a = 0; a < 3; ++a) {
                int o1 = (a == 0) ? 1 : 0;
                int o2 = (a == 2) ? 1 : 2;
                v2f tc2 = v2f{entry[o1], entry[o2]};
                {
                    #pragma clang fp contract(off)
                    v2f m2 = tc2 * v2f{rd[a], rd[a]};                // pk mul (rounded)
                    v2f p2 = v2f{ro[a], ro[a]} + m2;                 // pk add (rounded)
                    inb[a][o1] = (p2.x >= loE[a]) && (p2.x <= hiE[a]);
                    inb[a][o2] = (p2.y >= loE[a]) && (p2.y <= hiE[a]);
                }
            }
            float tn = BIG;
            #pragma unroll
            for (int cnd = 0; cnd < 3; ++cnd) {
                int a1 = (cnd == 0) ? 1 : 0;
                int a2 = (cnd == 2) ? 1 : 2;
                bool v = (entry[cnd] >= 0.0f) && inb[a1][cnd] && inb[a2][cnd];
                if (v) tn = fminf(tn, entry[cnd]);
            }
            if (tn < best) { best = tn; bestb = b; }  // strict <: first-min within half
        }

        // Liveness barrier on outputs: each rep's results are consumed -> no DCE.
        int ki = (int)keep;
        asm volatile("" : "+v"(best), "+v"(bestb), "+v"(ki));
        keep = (ki != 0);
    }

    // Pair combine: odd lane's half (boxes 16..31) wins only on STRICT < .
    float o_best  = __shfl_xor(best, 1, 64);
    int   o_bestb = __shfl_xor(bestb, 1, 64);
    int   o_keep  = __shfl_xor((int)keep, 1, 64);

    if (par == 0) {
        bool k = keep || (o_keep != 0);
        float fb = best; int fi = bestb;
        if (o_best < fb) { fb = o_best; fi = o_bestb; }   // hi half only if strictly smaller
        out_idx[ray]  = k ? (float)fi : -1.0f;
        out_dist[ray] = k ? fb : -1.0f;
    }
}

extern "C" void kernel_launch(void* const* d_in, const int* in_sizes, int n_in,
                              void* d_out, int out_size, void* d_ws, size_t ws_size,
                              hipStream_t stream) {
    const float* rays_o = (const float*)d_in[0];
    const float* rays_d = (const float*)d_in[1];
    const float* bbox   = (const float*)d_in[2];
    int R = in_sizes[0] / 3;

    float* out = (float*)d_out;
    float* out_idx  = out;
    float* out_dist = out + R;

    const int threads = 256;
    const long long total = 2LL * R;                 // 2 threads per ray
    const int blocks = (int)((total + threads - 1) / threads);
    ray_aabb_kernel<<<blocks, threads, 0, stream>>>(rays_o, rays_d, bbox,
                                                    out_idx, out_dist, R);
}

// Round 13
// 21.305 us; speedup vs baseline: 2.2837x; 2.2837x over previous
//
#include <hip/hip_runtime.h>

// Ray-AABB nearest intersection. R rays x B boxes. 2 lanes per ray (even: boxes
// 0..15, odd: 16..31), combined via shfl_xor with strict-< (np.argmin first-min).
//
// Bit-exactness (validated absmax 0.0 R4-R11): Markstein div == RN div given
// exact y=RN(1/rd); contract(off)-equivalent separate mul/add for p=ro+t*rd;
// own-axis band check elided; best init = BIG.
// med3 in-band: p,loE,hiE finite and loE<=hiE => med3(p,loE,hiE)==p <=> loE<=p<=hiE
// (numerically identical to (p>=loE)&&(p<=hiE), incl. +-0 which compares equal).
//
// R11 probe facts: VGPR=24 (occupancy NOT register-limited), VALUBusy 71-75%,
// SQ_LDS_BANK_CONFLICT ~1.59M cy/rep (~15% of cycles): even/odd lane broadcast
// addresses were 768B apart == same banks -> every ds_read_b128 serialized 2x.
// Fix: pair-interleaved slots, partners 48B apart -> disjoint bank quads.
// Block=1024 (512 WGs vs 2048) to shrink dispatch ramp.

typedef float v2f __attribute__((ext_vector_type(2)));

constexpr int BMAX = 32;
constexpr int HALF = BMAX / 2;

__global__ __launch_bounds__(1024) void ray_aabb_kernel(
    const float* __restrict__ rays_o,
    const float* __restrict__ rays_d,
    const float* __restrict__ bbox,
    float* __restrict__ out_idx,
    float* __restrict__ out_dist,
    int R)
{
    const float BIG = 10000000000.0f;
    const float EPS = 1e-4f;

    // slot(b) = (b&15)*2 + (b>>4): box bi (even lane) and 16+bi (odd lane) sit in
    // adjacent 48B slots -> their ds_read_b128 broadcast addresses differ by 48B
    // (banks 12 apart, disjoint quads) instead of 768B (same banks, 2x serialize).
    // Per slot: q0=(lo0,hi0,lo1,hi1)  q1=(lo2,hi2,loE0,loE1)  q2=(loE2,hiE0,hiE1,hiE2)
    __shared__ float4 s_q[BMAX][3];

    int t = threadIdx.x;
    if (t < BMAX) {
        int b = t;
        int slot = (b & 15) * 2 + (b >> 4);
        float lo[3], hi[3], loE[3], hiE[3];
        #pragma unroll
        for (int a = 0; a < 3; ++a) {
            float c = bbox[b * 6 + a];
            float s = bbox[b * 6 + 3 + a];
            float h  = __fmul_rn(s, 0.5f);
            lo[a]  = __fsub_rn(c, h);
            hi[a]  = __fadd_rn(c, h);
            loE[a] = __fsub_rn(lo[a], EPS);
            hiE[a] = __fadd_rn(hi[a], EPS);
        }
        s_q[slot][0] = make_float4(lo[0], hi[0], lo[1], hi[1]);
        s_q[slot][1] = make_float4(lo[2], hi[2], loE[0], loE[1]);
        s_q[slot][2] = make_float4(loE[2], hiE[0], hiE[1], hiE[2]);
    }
    __syncthreads();

    // 2 threads per ray: parity selects box half.
    int gid  = blockIdx.x * blockDim.x + threadIdx.x;
    int ray  = gid >> 1;
    int par  = gid & 1;          // 0: boxes [0,16)  1: boxes [16,32)
    if (ray >= R) return;
    int b0   = par * HALF;

    float ro[3], rd[3], y[3];
    #pragma unroll
    for (int a = 0; a < 3; ++a) {
        ro[a] = rays_o[ray * 3 + a];
        float d = rays_d[ray * 3 + a];
        rd[a] = (d == 0.0f) ? 1e-8f : d;
        y[a]  = __fdiv_rn(1.0f, rd[a]);   // exact RN reciprocal (Markstein precondition)
    }

    bool  keep  = false;
    float best  = BIG;   // all-invalid half => (BIG, b0); matches np argmin-of-all-BIG
    int   bestb = b0;

    #pragma unroll 4
    for (int bi = 0; bi < HALF; ++bi) {
        int slot = bi * 2 + par;
        int b    = b0 + bi;            // true box index
        float4 q0 = s_q[slot][0];
        float4 q1 = s_q[slot][1];
        float4 q2 = s_q[slot][2];
        v2f bnd[3];                    // {lo,hi} per axis
        bnd[0] = v2f{q0.x, q0.y};
        bnd[1] = v2f{q0.z, q0.w};
        bnd[2] = v2f{q1.x, q1.y};
        float loE[3] = {q1.z, q1.w, q2.x};
        float hiE[3] = {q2.y, q2.z, q2.w};

        float entry[3], exitv[3];
        #pragma unroll
        for (int a = 0; a < 3; ++a) {
            // Packed Markstein: both bounds' divisions in one chain of pk ops.
            v2f ys  = v2f{y[a], y[a]};
            v2f rs  = v2f{rd[a], rd[a]};
            v2f d2  = bnd[a] - v2f{ro[a], ro[a]};               // pk sub
            v2f q0v = d2 * ys;                                   // pk mul
            v2f e   = __builtin_elementwise_fma(rs, -q0v, d2);   // pk fma (exact residual)
            v2f qv  = __builtin_elementwise_fma(e, ys, q0v);     // pk fma == RN(d2/rd)
            entry[a] = fminf(qv.x, qv.y);
            exitv[a] = fmaxf(qv.x, qv.y);
        }
        float tmm = fmaxf(entry[0], fmaxf(entry[1], entry[2]));
        float tmx = fminf(exitv[0], fminf(exitv[1], exitv[2]));
        keep = keep || ((tmm < tmx) && (tmx > 0.0f));

        // In-band via v_med3_f32: for axis a, candidates from the two OTHER axes
        // (packed p-comp, separate mul/add roundings).
        bool inb[3][3];
        #pragma unroll
        for (int a = 0; a < 3; ++a) {
            int o1 = (a == 0) ? 1 : 0;
            int o2 = (a == 2) ? 1 : 2;
            v2f tc2 = v2f{entry[o1], entry[o2]};
            {
                #pragma clang fp contract(off)
                v2f m2 = tc2 * v2f{rd[a], rd[a]};                // pk mul (rounded)
                v2f p2 = v2f{ro[a], ro[a]} + m2;                 // pk add (rounded)
                inb[a][o1] = (__builtin_amdgcn_fmed3f(p2.x, loE[a], hiE[a]) == p2.x);
                inb[a][o2] = (__builtin_amdgcn_fmed3f(p2.y, loE[a], hiE[a]) == p2.y);
            }
        }
        float tn = BIG;
        #pragma unroll
        for (int cnd = 0; cnd < 3; ++cnd) {
            int a1 = (cnd == 0) ? 1 : 0;
            int a2 = (cnd == 2) ? 1 : 2;
            bool v = (entry[cnd] >= 0.0f) && inb[a1][cnd] && inb[a2][cnd];
            if (v) tn = fminf(tn, entry[cnd]);
        }
        if (tn < best) { best = tn; bestb = b; }  // strict <: first-min within half
    }

    // Pair combine: odd lane's half (boxes 16..31) wins only on STRICT < .
    float o_best  = __shfl_xor(best, 1, 64);
    int   o_bestb = __shfl_xor(bestb, 1, 64);
    int   o_keep  = __shfl_xor((int)keep, 1, 64);

    if (par == 0) {
        bool k = keep || (o_keep != 0);
        float fb = best; int fi = bestb;
        if (o_best < fb) { fb = o_best; fi = o_bestb; }   // hi half only if strictly smaller
        out_idx[ray]  = k ? (float)fi : -1.0f;
        out_dist[ray] = k ? fb : -1.0f;
    }
}

extern "C" void kernel_launch(void* const* d_in, const int* in_sizes, int n_in,
                              void* d_out, int out_size, void* d_ws, size_t ws_size,
                              hipStream_t stream) {
    const float* rays_o = (const float*)d_in[0];
    const float* rays_d = (const float*)d_in[1];
    const float* bbox   = (const float*)d_in[2];
    int R = in_sizes[0] / 3;

    float* out = (float*)d_out;
    float* out_idx  = out;
    float* out_dist = out + R;

    const int threads = 1024;   // fewer WGs -> shorter dispatch ramp
    const long long total = 2LL * R;                 // 2 threads per ray
    const int blocks = (int)((total + threads - 1) / threads);
    ray_aabb_kernel<<<blocks, threads, 0, stream>>>(rays_o, rays_d, bbox,
                                                    out_idx, out_dist, R);
}